// Round 8
// baseline (169.651 us; speedup 1.0000x reference)
//
#include <hip/hip_runtime.h>
#include <hip/hip_bf16.h>

#define NUM_BUCKETS 8192
#define WAVE 64

typedef float f32x4 __attribute__((ext_vector_type(4)));

// Kernel 1: exclusive prefix sum of row_lengths -> offs[0..B].
// Single block, 1024 threads, 16 elems/thread, shfl-based (~4 barriers/chunk).
__global__ __launch_bounds__(1024) void scan_rows_kernel(
    const int* __restrict__ row_len, int* __restrict__ offs, int B) {
    __shared__ int wave_sums[16];
    __shared__ int carry_s;
    const int t = threadIdx.x;
    const int wave = t >> 6, lane = t & 63;
    if (t == 0) carry_s = 0;
    __syncthreads();
    const int CHUNK = 1024 * 16;
    for (int base = 0; base < B; base += CHUNK) {
        int v[16];
        const int idx0 = base + t * 16;
        int local = 0;
        #pragma unroll
        for (int e = 0; e < 16; ++e) {
            const int i = idx0 + e;
            const int x = (i < B) ? row_len[i] : 0;
            v[e] = local;          // exclusive within thread
            local += x;
        }
        int incl = local;
        #pragma unroll
        for (int d = 1; d < 64; d <<= 1) {
            const int y = __shfl_up(incl, d, 64);
            if (lane >= d) incl += y;
        }
        if (lane == 63) wave_sums[wave] = incl;
        __syncthreads();
        if (wave == 0) {
            int s = (lane < 16) ? wave_sums[lane] : 0;
            #pragma unroll
            for (int d = 1; d < 16; d <<= 1) {
                const int y = __shfl_up(s, d, 64);
                if (lane >= d) s += y;
            }
            if (lane < 16) wave_sums[lane] = s;
        }
        __syncthreads();
        const int carry = carry_s;
        const int wave_excl = (wave == 0) ? 0 : wave_sums[wave - 1];
        const int texcl = carry + wave_excl + (incl - local);
        #pragma unroll
        for (int e = 0; e < 16; ++e) {
            const int i = idx0 + e;
            if (i < B) offs[i] = texcl + v[e];
        }
        if (t == 0 && base + CHUNK >= B) offs[B] = carry + wave_sums[15];
        __syncthreads();
        if (t == 0) carry_s = carry + wave_sums[15];
        __syncthreads();
    }
}

// Kernel 2: one wave per row, NO LDS. Phase 1: issue the row's 32 zero
// dwordx4 stores immediately (register source, zero deps — fillBuffer's
// inner loop). Phase 2 (overlaps the drain): lane i holds pair i of the
// row; 63-step shfl ring merges duplicate ids exactly (sum + lowest-lane
// writer). Phase 3: s_waitcnt vmcnt(0) (zeros ACKed, lines dirty in L2),
// then writer lanes overwrite their single dword. Rows with n>64 use a
// global-atomic fallback after the drain (correct for any raggedness).
__global__ __launch_bounds__(WAVE) void nhot_wave_kernel(
    const int* __restrict__ ids, const float* __restrict__ w,
    const int* __restrict__ offs, float* __restrict__ out) {
    const int r = blockIdx.x;
    const int lane = threadIdx.x;

    float* rowp = out + (size_t)r * NUM_BUCKETS;
    f32x4* outv = reinterpret_cast<f32x4*>(rowp);
    const f32x4 z = {0.f, 0.f, 0.f, 0.f};

    // Phase 1: blast zeros for the whole row (32 x 1KiB/wave instructions)
    #pragma unroll
    for (int k = 0; k < NUM_BUCKETS / 4 / WAVE; ++k)
        outv[k * WAVE + lane] = z;

    // Phase 2: payload into registers + in-register dupe merge
    const int s = offs[r];
    const int e = offs[r + 1];
    const int n = e - s;

    if (n <= WAVE) {
        int id = -1; float wt = 0.f;
        if (lane < n) { id = ids[s + lane]; wt = w[s + lane]; }
        float sum = wt;
        bool writer = (lane < n);
        #pragma unroll
        for (int d = 1; d < WAVE; ++d) {
            const int src = (lane + d) & (WAVE - 1);
            const int oid = __shfl(id, src, WAVE);
            const float ow = __shfl(wt, src, WAVE);
            const bool m = (oid == id) && (lane < n);
            if (m) sum += ow;
            if (m && src < lane) writer = false;  // lowest lane writes
        }
        asm volatile("s_waitcnt vmcnt(0)" ::: "memory");  // zeros ACKed at L2
        if (writer) rowp[id] = sum;
    } else {
        // general ragged fallback (not exercised when L <= 64)
        asm volatile("s_waitcnt vmcnt(0)" ::: "memory");
        for (int i = s + lane; i < e; i += WAVE)
            atomicAdd(&rowp[ids[i]], w[i]);
    }
}

extern "C" void kernel_launch(void* const* d_in, const int* in_sizes, int n_in,
                              void* d_out, int out_size, void* d_ws, size_t ws_size,
                              hipStream_t stream) {
    const int*   ids     = (const int*)d_in[0];    // values (NNZ,1) int32
    const int*   row_len = (const int*)d_in[1];    // row_lengths (B,1) int32
    const float* wvals   = (const float*)d_in[2];  // weight_values (NNZ,1) f32
    // d_in[3] = weight_row_lengths (unused by reference)

    const int B = in_sizes[1];
    float* out = (float*)d_out;
    int* offs = (int*)d_ws;  // needs (B+1)*4 bytes

    scan_rows_kernel<<<1, 1024, 0, stream>>>(row_len, offs, B);
    nhot_wave_kernel<<<B, WAVE, 0, stream>>>(ids, wvals, offs, out);
}